// Round 5
// baseline (1302.358 us; speedup 1.0000x reference)
//
#include <hip/hip_runtime.h>
#include <hip/hip_bf16.h>

#define NNUE_INPUTS 41024
#define NV4_ROW (NNUE_INPUTS / 4)   // 10256 float4 chunks per row (exact)
#define L1N 128
#define L2N 32
#define L3N 32
#define MAX_ACT 512                  // per-perspective per-row capacity

__device__ __forceinline__ float clip01(float x) {
    return fminf(fmaxf(x, 0.0f), 1.0f);
}

// ---------------- Kernel 1: pure streaming scan ----------------
// Grid = 2*HALF blocks. Blocks [0,HALF) scan w_in (persp 0), [HALF,2*HALF) scan b_in.
// Flat grid-stride over the row-major mask buffer; emit active feature indices
// into per-row global lists via device atomics.
__global__ __launch_bounds__(256, 8) void nnue_scan_kernel(
    const float* __restrict__ w_in, const float* __restrict__ b_in,
    int* __restrict__ cnt,          // [2][rows]
    int* __restrict__ idx,          // [2][rows][MAX_ACT]
    int rows)
{
    const int  half = gridDim.x >> 1;
    const int  p    = (blockIdx.x >= half) ? 1 : 0;
    const int  blk  = p ? (blockIdx.x - half) : blockIdx.x;
    const float4* src = (const float4*)(p ? b_in : w_in);
    int* mycnt = cnt + (size_t)p * rows;
    int* myidx = idx + (size_t)p * rows * MAX_ACT;

    const long NV4    = (long)rows * NV4_ROW;      // 42,008,576 chunks
    const long tcount = (long)half * 256;          // threads per perspective

    auto put = [&](int e) {
        const int r  = (unsigned)e / NNUE_INPUTS;  // magic-mul div by constant
        const int f  = e - r * NNUE_INPUTS;
        const int pp = atomicAdd(&mycnt[r], 1);
        myidx[(size_t)r * MAX_ACT + (pp & (MAX_ACT - 1))] = f;
    };
    auto emit = [&](const float4& x, long v) {
        const float s = (x.x + x.y) + (x.z + x.w);
        if (s != 0.0f) {
            const int e = (int)(v * 4);
            if (x.x != 0.0f) put(e);
            if (x.y != 0.0f) put(e + 1);
            if (x.z != 0.0f) put(e + 2);
            if (x.w != 0.0f) put(e + 3);
        }
    };

    long v = (long)blk * 256 + threadIdx.x;
    // bulk: 4 independent 16B loads in flight per iteration
    for (; v + 3 * tcount < NV4; v += 4 * tcount) {
        const float4 x0 = src[v];
        const float4 x1 = src[v + tcount];
        const float4 x2 = src[v + 2 * tcount];
        const float4 x3 = src[v + 3 * tcount];
        const float s = (((x0.x + x0.y) + (x0.z + x0.w)) + ((x1.x + x1.y) + (x1.z + x1.w)))
                      + (((x2.x + x2.y) + (x2.z + x2.w)) + ((x3.x + x3.y) + (x3.z + x3.w)));
        if (__any(s != 0.0f)) {     // one wave-level branch per 256B/thread window
            emit(x0, v);
            emit(x1, v + tcount);
            emit(x2, v + 2 * tcount);
            emit(x3, v + 3 * tcount);
        }
    }
    for (; v < NV4; v += tcount) {
        const float4 x = src[v];
        emit(x, v);
    }
}

// ---------------- Kernel 2: gather + tiny MLP, one block per row ----------------
__global__ __launch_bounds__(256, 8) void nnue_tail_kernel(
    const float* __restrict__ us, const float* __restrict__ them,
    const float* __restrict__ W_ft, const float* __restrict__ b_ft,
    const float* __restrict__ W1, const float* __restrict__ b1,
    const float* __restrict__ W2, const float* __restrict__ b2,
    const float* __restrict__ Wo, const float* __restrict__ bo,
    const int* __restrict__ cnt, const int* __restrict__ idx,
    float* __restrict__ out, int rows)
{
    __shared__ float s_w[L1N];
    __shared__ float s_b[L1N];
    __shared__ float s_l0[2 * L1N];
    __shared__ float s_part[8][L2N];
    __shared__ float s_l1[L2N];
    __shared__ float s_l2[L3N];

    const int row = blockIdx.x;
    const int tid = threadIdx.x;
    const float u = us[row];
    const float t = them[row];

    // ---- gather W_ft rows for active features ----
    {
        const int  c    = tid & (L1N - 1);
        const int  p    = (tid >= L1N) ? 1 : 0;
        const int  K    = min(cnt[(size_t)p * rows + row], MAX_ACT);
        const int* lst  = idx + ((size_t)p * rows + row) * MAX_ACT;
        const float* Wc = W_ft + c;
        float acc = b_ft[c];
        int k = 0;
        for (; k + 4 <= K; k += 4) {
            const int i0 = lst[k], i1 = lst[k + 1], i2 = lst[k + 2], i3 = lst[k + 3];
            const float f0 = Wc[(size_t)i0 * L1N];
            const float f1 = Wc[(size_t)i1 * L1N];
            const float f2 = Wc[(size_t)i2 * L1N];
            const float f3 = Wc[(size_t)i3 * L1N];
            acc += f0; acc += f1; acc += f2; acc += f3;
        }
        for (; k < K; ++k) acc += Wc[(size_t)lst[k] * L1N];
        if (p) s_b[c] = acc; else s_w[c] = acc;
    }
    __syncthreads();

    // ---- perspective mix + clip -> l0 [256] ----
    if (tid < L1N) {
        const float wv = s_w[tid], bv = s_b[tid];
        s_l0[tid]       = clip01(u * wv + t * bv);
        s_l0[L1N + tid] = clip01(u * bv + t * wv);
    }
    __syncthreads();

    // ---- l1 = clip(l0 @ W1 + b1): 8 chunks x 32 outputs ----
    {
        const int o  = tid & 31;
        const int ch = tid >> 5;
        float a = 0.0f;
        const int k0 = ch * 32;
        #pragma unroll
        for (int k = 0; k < 32; ++k) a += s_l0[k0 + k] * W1[(k0 + k) * L2N + o];
        s_part[ch][o] = a;
    }
    __syncthreads();
    if (tid < L2N) {
        float a = b1[tid];
        #pragma unroll
        for (int j = 0; j < 8; ++j) a += s_part[j][tid];
        s_l1[tid] = clip01(a);
    }
    __syncthreads();

    // ---- l2 = clip(l1 @ W2 + b2) ----
    if (tid < L3N) {
        float a = b2[tid];
        #pragma unroll
        for (int k = 0; k < L2N; ++k) a += s_l1[k] * W2[k * L3N + tid];
        s_l2[tid] = clip01(a);
    }
    __syncthreads();

    // ---- out = l2 @ Wo + bo ----
    if (tid == 0) {
        float a = bo[0];
        #pragma unroll
        for (int k = 0; k < L3N; ++k) a += s_l2[k] * Wo[k];
        out[row] = a;
    }
}

extern "C" void kernel_launch(void* const* d_in, const int* in_sizes, int n_in,
                              void* d_out, int out_size, void* d_ws, size_t ws_size,
                              hipStream_t stream) {
    const float* us   = (const float*)d_in[0];
    const float* them = (const float*)d_in[1];
    const float* w_in = (const float*)d_in[2];
    const float* b_in = (const float*)d_in[3];
    const float* W_ft = (const float*)d_in[4];
    const float* b_ft = (const float*)d_in[5];
    const float* W1   = (const float*)d_in[6];
    const float* b1   = (const float*)d_in[7];
    const float* W2   = (const float*)d_in[8];
    const float* b2   = (const float*)d_in[9];
    const float* Wo   = (const float*)d_in[10];
    const float* bo   = (const float*)d_in[11];
    float* out = (float*)d_out;

    const int rows = in_sizes[0];  // 4096

    // ws layout: cnt[2][rows] then idx[2][rows][MAX_ACT]
    int* cnt = (int*)d_ws;
    int* idx = cnt + 2 * (size_t)rows;

    // zero the per-row counters (d_ws is poisoned 0xAA before every launch)
    hipMemsetAsync(cnt, 0, 2 * (size_t)rows * sizeof(int), stream);

    // scan: 2048 blocks (8/CU at 256 thr), halves split w/b perspectives
    nnue_scan_kernel<<<dim3(2048), dim3(256), 0, stream>>>(w_in, b_in, cnt, idx, rows);

    // gather + MLP
    nnue_tail_kernel<<<dim3(rows), dim3(256), 0, stream>>>(
        us, them, W_ft, b_ft, W1, b1, W2, b2, Wo, bo, cnt, idx, out, rows);
}

// Round 6
// 1244.090 us; speedup vs baseline: 1.0468x; 1.0468x over previous
//
#include <hip/hip_runtime.h>
#include <hip/hip_bf16.h>

#define NNUE_INPUTS 41024
#define L1N 128
#define L2N 32
#define L3N 32
#define MAX_ACT 512     // per-perspective capacity; mean ~30 actives
#define NV8 (NNUE_INPUTS / 8)      // 5128 chunks of 8 floats (32B)
#define BULK 20                    // 20*256 = 5120 uniform chunks; tail = 8

typedef float f4 __attribute__((ext_vector_type(4)));

__device__ __forceinline__ float clip01(float x) {
    return fminf(fmaxf(x, 0.0f), 1.0f);
}

__device__ __forceinline__ f4 ntload(const f4* p) {
    return __builtin_nontemporal_load(p);   // global_load_dwordx4 ... nt
}

__global__ __launch_bounds__(256, 4) void nnue_fused_kernel(
    const float* __restrict__ us, const float* __restrict__ them,
    const float* __restrict__ w_in, const float* __restrict__ b_in,
    const float* __restrict__ W_ft, const float* __restrict__ b_ft,
    const float* __restrict__ W1, const float* __restrict__ b1,
    const float* __restrict__ W2, const float* __restrict__ b2,
    const float* __restrict__ Wo, const float* __restrict__ bo,
    float* __restrict__ out)
{
    __shared__ int   s_idx_w[MAX_ACT];
    __shared__ int   s_idx_b[MAX_ACT];
    __shared__ int   s_cnt[2];
    __shared__ float s_w[L1N];
    __shared__ float s_b[L1N];
    __shared__ float s_l0[2 * L1N];
    __shared__ float s_part[8][L2N];
    __shared__ float s_l1[L2N];
    __shared__ float s_l2[L3N];

    const int row = blockIdx.x;
    const int tid = threadIdx.x;

    if (tid < 2) s_cnt[tid] = 0;
    const float u = us[row];
    const float t = them[row];
    __syncthreads();

    const f4* wr = (const f4*)(w_in + (size_t)row * NNUE_INPUTS);
    const f4* br = (const f4*)(b_in + (size_t)row * NNUE_INPUTS);

    auto process = [&](int v, const f4& a0, const f4& a1, const f4& c0, const f4& c1) {
        const float sw = ((a0[0] + a0[1]) + (a0[2] + a0[3])) + ((a1[0] + a1[1]) + (a1[2] + a1[3]));
        const float sb = ((c0[0] + c0[1]) + (c0[2] + c0[3])) + ((c1[0] + c1[1]) + (c1[2] + c1[3]));
        if (__any((sw != 0.0f) || (sb != 0.0f))) {
            const int base = v * 8;
            if (sw != 0.0f) {
                unsigned m = (a0[0] != 0.0f ?   1u : 0u) | (a0[1] != 0.0f ?   2u : 0u)
                           | (a0[2] != 0.0f ?   4u : 0u) | (a0[3] != 0.0f ?   8u : 0u)
                           | (a1[0] != 0.0f ?  16u : 0u) | (a1[1] != 0.0f ?  32u : 0u)
                           | (a1[2] != 0.0f ?  64u : 0u) | (a1[3] != 0.0f ? 128u : 0u);
                while (m) {
                    const int b = __ffs(m) - 1; m &= m - 1;
                    const int p = atomicAdd(&s_cnt[0], 1);
                    s_idx_w[p & (MAX_ACT - 1)] = base + b;
                }
            }
            if (sb != 0.0f) {
                unsigned m = (c0[0] != 0.0f ?   1u : 0u) | (c0[1] != 0.0f ?   2u : 0u)
                           | (c0[2] != 0.0f ?   4u : 0u) | (c0[3] != 0.0f ?   8u : 0u)
                           | (c1[0] != 0.0f ?  16u : 0u) | (c1[1] != 0.0f ?  32u : 0u)
                           | (c1[2] != 0.0f ?  64u : 0u) | (c1[3] != 0.0f ? 128u : 0u);
                while (m) {
                    const int b = __ffs(m) - 1; m &= m - 1;
                    const int p = atomicAdd(&s_cnt[1], 1);
                    s_idx_b[p & (MAX_ACT - 1)] = base + b;
                }
            }
        }
    };

    // ---- Phase 1: distance-1 pipelined scan with NON-TEMPORAL mask loads ----
    {
        int v = tid;
        f4 a0 = ntload(&wr[2 * v]), a1 = ntload(&wr[2 * v + 1]);
        f4 c0 = ntload(&br[2 * v]), c1 = ntload(&br[2 * v + 1]);
        #pragma unroll 1
        for (int i = 0; i < BULK - 1; ++i) {
            const int vn = v + 256;
            const f4 na0 = ntload(&wr[2 * vn]), na1 = ntload(&wr[2 * vn + 1]);
            const f4 nc0 = ntload(&br[2 * vn]), nc1 = ntload(&br[2 * vn + 1]);
            process(v, a0, a1, c0, c1);
            a0 = na0; a1 = na1; c0 = nc0; c1 = nc1;
            v = vn;
        }
        process(v, a0, a1, c0, c1);
        // tail: chunks [5120, 5128) on threads 0..7
        const int vt = BULK * 256 + tid;
        if (vt < NV8) {
            process(vt, ntload(&wr[2 * vt]), ntload(&wr[2 * vt + 1]),
                        ntload(&br[2 * vt]), ntload(&br[2 * vt + 1]));
        }
    }
    __syncthreads();

    const int kw = min(s_cnt[0], MAX_ACT);
    const int kb = min(s_cnt[1], MAX_ACT);

    // ---- Phase 2: gather W_ft rows (cached — real reuse across blocks) ----
    {
        const int  c    = tid & (L1N - 1);
        const bool is_b = tid >= L1N;
        const int* lst  = is_b ? s_idx_b : s_idx_w;
        const int  K    = is_b ? kb : kw;
        const float* Wc = W_ft + c;
        float acc = b_ft[c];
        int k = 0;
        for (; k + 4 <= K; k += 4) {
            const int i0 = lst[k], i1 = lst[k + 1], i2 = lst[k + 2], i3 = lst[k + 3];
            const float f0 = Wc[(size_t)i0 * L1N];
            const float f1 = Wc[(size_t)i1 * L1N];
            const float f2 = Wc[(size_t)i2 * L1N];
            const float f3 = Wc[(size_t)i3 * L1N];
            acc += f0; acc += f1; acc += f2; acc += f3;
        }
        for (; k < K; ++k) acc += Wc[(size_t)lst[k] * L1N];
        if (is_b) s_b[c] = acc; else s_w[c] = acc;
    }
    __syncthreads();

    // ---- Phase 3: perspective mix + clip -> l0 [256] ----
    if (tid < L1N) {
        const float wv = s_w[tid], bv = s_b[tid];
        s_l0[tid]       = clip01(u * wv + t * bv);
        s_l0[L1N + tid] = clip01(u * bv + t * wv);
    }
    __syncthreads();

    // ---- l1 = clip(l0 @ W1 + b1): 8 chunks x 32 outputs ----
    {
        const int o  = tid & 31;
        const int ch = tid >> 5;
        float a = 0.0f;
        const int k0 = ch * 32;
        #pragma unroll
        for (int k = 0; k < 32; ++k) a += s_l0[k0 + k] * W1[(k0 + k) * L2N + o];
        s_part[ch][o] = a;
    }
    __syncthreads();
    if (tid < L2N) {
        float a = b1[tid];
        #pragma unroll
        for (int j = 0; j < 8; ++j) a += s_part[j][tid];
        s_l1[tid] = clip01(a);
    }
    __syncthreads();

    // ---- l2 = clip(l1 @ W2 + b2) ----
    if (tid < L3N) {
        float a = b2[tid];
        #pragma unroll
        for (int k = 0; k < L2N; ++k) a += s_l1[k] * W2[k * L3N + tid];
        s_l2[tid] = clip01(a);
    }
    __syncthreads();

    // ---- out = l2 @ Wo + bo ----
    if (tid == 0) {
        float a = bo[0];
        #pragma unroll
        for (int k = 0; k < L3N; ++k) a += s_l2[k] * Wo[k];
        out[row] = a;
    }
}

extern "C" void kernel_launch(void* const* d_in, const int* in_sizes, int n_in,
                              void* d_out, int out_size, void* d_ws, size_t ws_size,
                              hipStream_t stream) {
    const float* us   = (const float*)d_in[0];
    const float* them = (const float*)d_in[1];
    const float* w_in = (const float*)d_in[2];
    const float* b_in = (const float*)d_in[3];
    const float* W_ft = (const float*)d_in[4];
    const float* b_ft = (const float*)d_in[5];
    const float* W1   = (const float*)d_in[6];
    const float* b1   = (const float*)d_in[7];
    const float* W2   = (const float*)d_in[8];
    const float* b2   = (const float*)d_in[9];
    const float* Wo   = (const float*)d_in[10];
    const float* bo   = (const float*)d_in[11];
    float* out = (float*)d_out;

    const int B = in_sizes[0];  // 4096
    nnue_fused_kernel<<<dim3(B), dim3(256), 0, stream>>>(
        us, them, w_in, b_in, W_ft, b_ft, W1, b1, W2, b2, Wo, bo, out);
}

// Round 7
// 1220.431 us; speedup vs baseline: 1.0671x; 1.0194x over previous
//
#include <hip/hip_runtime.h>
#include <hip/hip_bf16.h>

#define NNUE_INPUTS 41024
#define L1N 128
#define L2N 32
#define L3N 32
#define MAX_ACT 512
#define NC_ROW (NNUE_INPUTS / 4)     // 10256 float4 chunks per row
#define NC_HALF (NC_ROW / 2)         // 5128 chunks per half-row (per wave)
#define WITER 20                     // 20*256 = 5120 chunks; tail = 8 per wave

typedef float f4 __attribute__((ext_vector_type(4)));

__device__ __forceinline__ float clip01(float x) {
    return fminf(fmaxf(x, 0.0f), 1.0f);
}

__global__ __launch_bounds__(256, 4) void nnue_fused_kernel(
    const float* __restrict__ us, const float* __restrict__ them,
    const float* __restrict__ w_in, const float* __restrict__ b_in,
    const float* __restrict__ W_ft, const float* __restrict__ b_ft,
    const float* __restrict__ W1, const float* __restrict__ b1,
    const float* __restrict__ W2, const float* __restrict__ b2,
    const float* __restrict__ Wo, const float* __restrict__ bo,
    float* __restrict__ out)
{
    __shared__ int   s_idx_w[MAX_ACT];
    __shared__ int   s_idx_b[MAX_ACT];
    __shared__ int   s_cnt[2];
    __shared__ float s_w[L1N];
    __shared__ float s_b[L1N];
    __shared__ float s_l0[2 * L1N];
    __shared__ float s_part[8][L2N];
    __shared__ float s_l1[L2N];
    __shared__ float s_l2[L3N];

    const int row  = blockIdx.x;
    const int tid  = threadIdx.x;
    const int wave = tid >> 6;          // 0..3
    const int lane = tid & 63;

    if (tid < 2) s_cnt[tid] = 0;
    const float u = us[row];
    const float t = them[row];
    __syncthreads();

    // ---- Phase 1: ONE dense contiguous stream per wave ----
    // waves 0,1 -> w-row halves 0,1 ; waves 2,3 -> b-row halves 0,1.
    {
        const int     p    = wave >> 1;                     // 0 = w, 1 = b
        const f4*     src  = (const f4*)((p ? b_in : w_in) + (size_t)row * NNUE_INPUTS);
        int*          mcnt = &s_cnt[p];
        int*          midx = p ? s_idx_b : s_idx_w;
        const int     base = (wave & 1) * NC_HALF;          // chunk offset of this wave's half

        auto emit = [&](const f4& x, int c) {               // c = chunk index in row
            const int e = c * 4;
            if (x[0] != 0.0f) { int q = atomicAdd(mcnt, 1); midx[q & (MAX_ACT - 1)] = e;     }
            if (x[1] != 0.0f) { int q = atomicAdd(mcnt, 1); midx[q & (MAX_ACT - 1)] = e + 1; }
            if (x[2] != 0.0f) { int q = atomicAdd(mcnt, 1); midx[q & (MAX_ACT - 1)] = e + 2; }
            if (x[3] != 0.0f) { int q = atomicAdd(mcnt, 1); midx[q & (MAX_ACT - 1)] = e + 3; }
        };
        auto proc4 = [&](int c0, const f4& x0, const f4& x1, const f4& x2, const f4& x3) {
            const float s = (((x0[0] + x0[1]) + (x0[2] + x0[3])) + ((x1[0] + x1[1]) + (x1[2] + x1[3])))
                          + (((x2[0] + x2[1]) + (x2[2] + x2[3])) + ((x3[0] + x3[1]) + (x3[2] + x3[3])));
            if (__any(s != 0.0f)) {
                emit(x0, c0);
                emit(x1, c0 + 64);
                emit(x2, c0 + 128);
                emit(x3, c0 + 192);
            }
        };

        // distance-1 pipelined: wave-iter i covers chunks [base+i*256, base+(i+1)*256)
        int c = base + lane;
        f4 x0 = src[c], x1 = src[c + 64], x2 = src[c + 128], x3 = src[c + 192];
        #pragma unroll 1
        for (int i = 0; i < WITER - 1; ++i) {
            const int cn = c + 256;
            const f4 n0 = src[cn], n1 = src[cn + 64], n2 = src[cn + 128], n3 = src[cn + 192];
            proc4(c, x0, x1, x2, x3);
            x0 = n0; x1 = n1; x2 = n2; x3 = n3;
            c = cn;
        }
        proc4(c, x0, x1, x2, x3);
        // tail: last 8 chunks of this wave's half on lanes 0..7
        if (lane < NC_HALF - WITER * 256) {
            const int ct = base + WITER * 256 + lane;
            const f4 x = src[ct];
            const float s = (x[0] + x[1]) + (x[2] + x[3]);
            if (__any(s != 0.0f)) { if (s != 0.0f) emit(x, ct); }
        }
    }
    __syncthreads();

    const int kw = min(s_cnt[0], MAX_ACT);
    const int kb = min(s_cnt[1], MAX_ACT);

    // ---- Phase 2: gather W_ft rows ----
    {
        const int  ch   = tid & (L1N - 1);
        const bool is_b = tid >= L1N;
        const int* lst  = is_b ? s_idx_b : s_idx_w;
        const int  K    = is_b ? kb : kw;
        const float* Wc = W_ft + ch;
        float acc = b_ft[ch];
        int k = 0;
        for (; k + 4 <= K; k += 4) {
            const int i0 = lst[k], i1 = lst[k + 1], i2 = lst[k + 2], i3 = lst[k + 3];
            const float f0 = Wc[(size_t)i0 * L1N];
            const float f1 = Wc[(size_t)i1 * L1N];
            const float f2 = Wc[(size_t)i2 * L1N];
            const float f3 = Wc[(size_t)i3 * L1N];
            acc += f0; acc += f1; acc += f2; acc += f3;
        }
        for (; k < K; ++k) acc += Wc[(size_t)lst[k] * L1N];
        if (is_b) s_b[ch] = acc; else s_w[ch] = acc;
    }
    __syncthreads();

    // ---- Phase 3: perspective mix + clip -> l0 [256] ----
    if (tid < L1N) {
        const float wv = s_w[tid], bv = s_b[tid];
        s_l0[tid]       = clip01(u * wv + t * bv);
        s_l0[L1N + tid] = clip01(u * bv + t * wv);
    }
    __syncthreads();

    // ---- l1 = clip(l0 @ W1 + b1): 8 chunks x 32 outputs ----
    {
        const int o  = tid & 31;
        const int ch = tid >> 5;
        float a = 0.0f;
        const int k0 = ch * 32;
        #pragma unroll
        for (int k = 0; k < 32; ++k) a += s_l0[k0 + k] * W1[(k0 + k) * L2N + o];
        s_part[ch][o] = a;
    }
    __syncthreads();
    if (tid < L2N) {
        float a = b1[tid];
        #pragma unroll
        for (int j = 0; j < 8; ++j) a += s_part[j][tid];
        s_l1[tid] = clip01(a);
    }
    __syncthreads();

    // ---- l2 = clip(l1 @ W2 + b2) ----
    if (tid < L3N) {
        float a = b2[tid];
        #pragma unroll
        for (int k = 0; k < L2N; ++k) a += s_l1[k] * W2[k * L3N + tid];
        s_l2[tid] = clip01(a);
    }
    __syncthreads();

    // ---- out = l2 @ Wo + bo ----
    if (tid == 0) {
        float a = bo[0];
        #pragma unroll
        for (int k = 0; k < L3N; ++k) a += s_l2[k] * Wo[k];
        out[row] = a;
    }
}

extern "C" void kernel_launch(void* const* d_in, const int* in_sizes, int n_in,
                              void* d_out, int out_size, void* d_ws, size_t ws_size,
                              hipStream_t stream) {
    const float* us   = (const float*)d_in[0];
    const float* them = (const float*)d_in[1];
    const float* w_in = (const float*)d_in[2];
    const float* b_in = (const float*)d_in[3];
    const float* W_ft = (const float*)d_in[4];
    const float* b_ft = (const float*)d_in[5];
    const float* W1   = (const float*)d_in[6];
    const float* b1   = (const float*)d_in[7];
    const float* W2   = (const float*)d_in[8];
    const float* b2   = (const float*)d_in[9];
    const float* Wo   = (const float*)d_in[10];
    const float* bo   = (const float*)d_in[11];
    float* out = (float*)d_out;

    const int B = in_sizes[0];  // 4096
    nnue_fused_kernel<<<dim3(B), dim3(256), 0, stream>>>(
        us, them, w_in, b_in, W_ft, b_ft, W1, b1, W2, b2, Wo, bo, out);
}